// Round 8
// baseline (597.168 us; speedup 1.0000x reference)
//
#include <hip/hip_runtime.h>
#include <hip/hip_bf16.h>

#define CAP 48

typedef short  s8v  __attribute__((ext_vector_type(8)));
typedef float  f4v  __attribute__((ext_vector_type(4)));

__device__ __forceinline__ unsigned short f2bf(float f) {
    unsigned u = __float_as_uint(f);
    u += 0x7FFFu + ((u >> 16) & 1u);      // RNE
    return (unsigned short)(u >> 16);
}
__device__ __forceinline__ float bflo(unsigned v) { return __uint_as_float(v << 16); }
__device__ __forceinline__ float bfhi(unsigned v) { return __uint_as_float(v & 0xffff0000u); }
__device__ __forceinline__ float bf2f(unsigned short b) { return __uint_as_float(((unsigned)b) << 16); }

// packed bf16x2 atomic add (device scope). Primary: HW pk_add_bf16; fallback: CAS.
__device__ __forceinline__ void atomic_pk_bf16(unsigned* p, unsigned v) {
#if __has_builtin(__builtin_amdgcn_global_atomic_fadd_v2bf16)
    typedef short s2v __attribute__((ext_vector_type(2)));
    __builtin_amdgcn_global_atomic_fadd_v2bf16((s2v*)p, *(s2v*)&v);
#else
    unsigned old = *p, assumed;
    do {
        assumed = old;
        unsigned nv = (unsigned)f2bf(bflo(assumed) + bflo(v)) |
                      ((unsigned)f2bf(bfhi(assumed) ? bfhi(assumed) + bfhi(v) : bfhi(v)) << 16);
        // recompute hi properly (ternary above is wrong-proof: just do it straight)
        nv = (unsigned)f2bf(bflo(assumed) + bflo(v)) | ((unsigned)f2bf(bfhi(assumed) + bfhi(v)) << 16);
        old = atomicCAS(p, assumed, nv);
    } while (old != assumed);
#endif
}

// ---- build src-CSR (src -> list of dsts) + dst degree ----------------------
__global__ __launch_bounds__(256) void k_csr(const int* __restrict__ src, const int* __restrict__ dst,
                                             int E, int* __restrict__ cntS, int* __restrict__ cntD,
                                             int* __restrict__ bucketS) {
    int e = blockIdx.x * 256 + threadIdx.x;
    if (e < E) {
        int s = src[e], d = dst[e];
        int slot = atomicAdd(&cntS[s], 1);
        if (slot < CAP) bucketS[(size_t)s * CAP + slot] = d;
        atomicAdd(&cntD[d], 1);
    }
}

__global__ __launch_bounds__(256) void k_invdeg(const int* __restrict__ cntD, float* __restrict__ invdeg, int n) {
    int i = blockIdx.x * 256 + threadIdx.x;
    if (i < n) invdeg[i] = 1.0f / fmaxf((float)cntD[i], 1.0f);
}

// ---- merged: pack 6 weights (y=0..5) + BN fold (y=6) -----------------------
__global__ __launch_bounds__(256) void k_prepack(const float* W0, const float* W1, const float* W2,
                                                 const float* W3, const float* W4, const float* W5,
                                                 unsigned short* P0, unsigned short* P1, unsigned short* P2,
                                                 unsigned short* P3, unsigned short* P4, unsigned short* P5,
                                                 const float* g1, const float* be1, const float* rm1, const float* rv1, const float* bl1,
                                                 const float* g2, const float* be2, const float* rm2, const float* rv2, const float* bl2,
                                                 float* P) {
    if (blockIdx.y == 6) {
        if (blockIdx.x == 0 && threadIdx.x < 128) {
            int i = threadIdx.x;
            float s1 = g1[i] * rsqrtf(rv1[i] + 1e-5f);
            P[i]       = s1;
            P[128 + i] = (bl1[i] - rm1[i]) * s1 + be1[i];
            float s2 = g2[i] * rsqrtf(rv2[i] + 1e-5f);
            P[256 + i] = s2;
            P[384 + i] = (bl2[i] - rm2[i]) * s2 + be2[i];
        }
        return;
    }
    const float* W; unsigned short* Pk; int JD;
    switch (blockIdx.y) {
        case 0: W = W0; Pk = P0; JD = 128; break;
        case 1: W = W1; Pk = P1; JD = 128; break;
        case 2: W = W2; Pk = P2; JD = 128; break;
        case 3: W = W3; Pk = P3; JD = 128; break;
        case 4: W = W4; Pk = P4; JD = 64;  break;
        default:W = W5; Pk = P5; JD = 64;  break;
    }
    int o = blockIdx.x * 256 + threadIdx.x;
    if (o >= 128 * JD) return;
    int j    = o & 7;
    int lane = (o >> 3) & 63;
    int t    = o >> 9;
    int nt   = t % (JD / 16);
    int kt   = t / (JD / 16);
    int k = kt * 32 + (lane >> 4) * 8 + j;
    int n = nt * 16 + (lane & 15);
    Pk[o] = f2bf(W[(size_t)k * JD + n]);
}

// ---- fp32 -> bf16 row-major convert ----------------------------------------
__global__ __launch_bounds__(256) void k_cvt(const float* __restrict__ in, unsigned short* __restrict__ out, int n4) {
    int i = blockIdx.x * 256 + threadIdx.x;
    if (i < n4) {
        float4 v = ((const float4*)in)[i];
        ushort4 o;
        o.x = f2bf(v.x); o.y = f2bf(v.y); o.z = f2bf(v.z); o.w = f2bf(v.w);
        ((ushort4*)out)[i] = o;
    }
}

// ---- push-style mean aggregation via packed bf16 atomics -------------------
// one wave per SRC node; row streamed once; per edge: acc[dst] += row*invdeg[dst].
// DW = uints (bf16 pairs) per row: 64 for 128-dim, 32 for 64-dim.
template<int DW>
__global__ __launch_bounds__(256) void k_push(const unsigned* __restrict__ feat, const int* __restrict__ cntS,
                                              const int* __restrict__ bucketS, const float* __restrict__ invdeg,
                                              unsigned* __restrict__ acc, int n) {
    int wv   = (blockIdx.x * 256 + threadIdx.x) >> 6;
    int lane = threadIdx.x & 63;
    if (wv >= n) return;
    int c = cntS[wv]; if (c > CAP) c = CAP;
    if (c == 0) return;
    // preload dst ids + their invdeg into lanes (c <= 48 < 64)
    int   dl = bucketS[(size_t)wv * CAP + (lane < CAP ? lane : CAP - 1)];
    float il = (lane < c) ? invdeg[dl] : 0.f;
    // stream own row
    float fx = 0.f, fy = 0.f;
    if (lane < DW) {
        unsigned rv = feat[(size_t)wv * DW + lane];
        fx = bflo(rv); fy = bfhi(rv);
    }
    for (int s = 0; s < c; s++) {
        int   d  = __shfl(dl, s);
        float iv = __shfl(il, s);
        if (lane < DW) {
            unsigned pv = (unsigned)f2bf(fx * iv) | ((unsigned)f2bf(fy * iv) << 16);
            atomic_pk_bf16(acc + (size_t)d * DW + lane, pv);
        }
    }
}

// ---- dense layer: dual MFMA (acc-mean side + root side), BN+ReLU epilogue --
// block = 32 nodes, 4 waves; wave = 32 rows x 32 cols. T3: also t3 = out @ Wl3.
template<bool T3>
__global__ __launch_bounds__(256) void k_dense(const unsigned short* __restrict__ accm,  // bf16 mean rows
                                               const unsigned short* __restrict__ feat,  // root rows
                                               const unsigned short* __restrict__ Bl, const unsigned short* __restrict__ Br,
                                               const float* __restrict__ scale, const float* __restrict__ shift,
                                               unsigned short* __restrict__ out,
                                               const unsigned short* __restrict__ W3p, unsigned short* __restrict__ t3,
                                               int n) {
    __shared__ unsigned short sH[T3 ? 32 * 136 : 8];
    const int tid  = threadIdx.x;
    const int wave = tid >> 6;
    const int lane = tid & 63;
    const int nb0  = blockIdx.x * 32;
    if (nb0 >= n) return;

    const int m = lane & 15;
    const int q = lane >> 4;
    const int nt0 = wave * 2;
    const int rg0 = min(nb0 + m,      n - 1);
    const int rg1 = min(nb0 + 16 + m, n - 1);

    f4v acc[2][2];
    #pragma unroll
    for (int mt = 0; mt < 2; mt++)
        #pragma unroll
        for (int c = 0; c < 2; c++) {
            acc[mt][c][0] = 0.f; acc[mt][c][1] = 0.f; acc[mt][c][2] = 0.f; acc[mt][c][3] = 0.f;
        }

    #pragma unroll
    for (int kt = 0; kt < 4; kt++) {
        const int ko = kt * 32 + q * 8;
        s8v a0  = *(const s8v*)(accm + (size_t)rg0 * 128 + ko);   // aggregated mean (bf16)
        s8v a1  = *(const s8v*)(accm + (size_t)rg1 * 128 + ko);
        s8v a0d = *(const s8v*)(feat + (size_t)rg0 * 128 + ko);   // root features
        s8v a1d = *(const s8v*)(feat + (size_t)rg1 * 128 + ko);
        #pragma unroll
        for (int c = 0; c < 2; c++) {
            s8v b  = *(const s8v*)(Bl + ((size_t)(kt * 8 + nt0 + c) * 64 + lane) * 8);
            acc[0][c] = __builtin_amdgcn_mfma_f32_16x16x32_bf16(a0, b, acc[0][c], 0, 0, 0);
            acc[1][c] = __builtin_amdgcn_mfma_f32_16x16x32_bf16(a1, b, acc[1][c], 0, 0, 0);
            s8v b2 = *(const s8v*)(Br + ((size_t)(kt * 8 + nt0 + c) * 64 + lane) * 8);
            acc[0][c] = __builtin_amdgcn_mfma_f32_16x16x32_bf16(a0d, b2, acc[0][c], 0, 0, 0);
            acc[1][c] = __builtin_amdgcn_mfma_f32_16x16x32_bf16(a1d, b2, acc[1][c], 0, 0, 0);
        }
    }

    float scv[2], shv[2];
    #pragma unroll
    for (int c = 0; c < 2; c++) {
        int col = (nt0 + c) * 16 + m;
        scv[c] = scale[col]; shv[c] = shift[col];
    }
    #pragma unroll
    for (int mt = 0; mt < 2; mt++) {
        #pragma unroll
        for (int reg = 0; reg < 4; reg++) {
            int rloc = mt * 16 + q * 4 + reg;
            int row  = nb0 + rloc;
            if (row < n) {
                #pragma unroll
                for (int c = 0; c < 2; c++) {
                    int col = (nt0 + c) * 16 + m;
                    float v = fmaxf(acc[mt][c][reg] * scv[c] + shv[c], 0.f);
                    unsigned short u = f2bf(v);
                    out[(size_t)row * 128 + col] = u;
                    if constexpr (T3) sH[rloc * 136 + col] = u;
                }
            }
        }
    }

    if constexpr (T3) {
        __syncthreads();
        f4v a3c[2];
        #pragma unroll
        for (int mt = 0; mt < 2; mt++) { a3c[mt][0] = 0.f; a3c[mt][1] = 0.f; a3c[mt][2] = 0.f; a3c[mt][3] = 0.f; }
        #pragma unroll
        for (int kt = 0; kt < 4; kt++) {
            const int ko = kt * 32 + q * 8;
            s8v a0 = *(const s8v*)(sH + m * 136 + ko);
            s8v a1 = *(const s8v*)(sH + (16 + m) * 136 + ko);
            s8v b  = *(const s8v*)(W3p + ((size_t)(kt * 4 + wave) * 64 + lane) * 8);
            a3c[0] = __builtin_amdgcn_mfma_f32_16x16x32_bf16(a0, b, a3c[0], 0, 0, 0);
            a3c[1] = __builtin_amdgcn_mfma_f32_16x16x32_bf16(a1, b, a3c[1], 0, 0, 0);
        }
        #pragma unroll
        for (int mt = 0; mt < 2; mt++) {
            #pragma unroll
            for (int reg = 0; reg < 4; reg++) {
                int row = nb0 + mt * 16 + q * 4 + reg;
                if (row < n) t3[(size_t)row * 64 + wave * 16 + m] = f2bf(a3c[mt][reg]);
            }
        }
    }
}

// ---- final: out = mean3(acc3) + hb2@Wr3 + bias (fp32) ----------------------
__global__ __launch_bounds__(256) void k_final(const unsigned short* __restrict__ hb2,
                                               const unsigned short* __restrict__ acc3,  // bf16 mean rows (64)
                                               const unsigned short* __restrict__ Bp, const float* __restrict__ bias,
                                               float* __restrict__ outf, int n) {
    const int tid  = threadIdx.x;
    const int wave = tid >> 6;
    const int lane = tid & 63;
    const int nb0  = blockIdx.x * 32;
    if (nb0 >= n) return;

    const int m = lane & 15;
    const int q = lane >> 4;
    const int rg0 = min(nb0 + m,      n - 1);
    const int rg1 = min(nb0 + 16 + m, n - 1);

    f4v acc[2];
    #pragma unroll
    for (int mt = 0; mt < 2; mt++) { acc[mt][0] = 0.f; acc[mt][1] = 0.f; acc[mt][2] = 0.f; acc[mt][3] = 0.f; }

    #pragma unroll
    for (int kt = 0; kt < 4; kt++) {
        const int ko = kt * 32 + q * 8;
        s8v a0 = *(const s8v*)(hb2 + (size_t)rg0 * 128 + ko);
        s8v a1 = *(const s8v*)(hb2 + (size_t)rg1 * 128 + ko);
        s8v b  = *(const s8v*)(Bp + ((size_t)(kt * 4 + wave) * 64 + lane) * 8);
        acc[0] = __builtin_amdgcn_mfma_f32_16x16x32_bf16(a0, b, acc[0], 0, 0, 0);
        acc[1] = __builtin_amdgcn_mfma_f32_16x16x32_bf16(a1, b, acc[1], 0, 0, 0);
    }

    const int col = wave * 16 + m;
    const float bv = bias[col];
    #pragma unroll
    for (int mt = 0; mt < 2; mt++) {
        #pragma unroll
        for (int reg = 0; reg < 4; reg++) {
            int rloc = mt * 16 + q * 4 + reg;
            int row  = nb0 + rloc;
            if (row < n)
                outf[(size_t)row * 64 + col] = acc[mt][reg] + bf2f(acc3[(size_t)row * 64 + col]) + bv;
        }
    }
}

extern "C" void kernel_launch(void* const* d_in, const int* in_sizes, int n_in,
                              void* d_out, int out_size, void* d_ws, size_t ws_size,
                              hipStream_t stream) {
    const float* x   = (const float*)d_in[0];
    const int*   ei  = (const int*)d_in[1];
    const float* Wl1 = (const float*)d_in[2];
    const float* bl1 = (const float*)d_in[3];
    const float* Wr1 = (const float*)d_in[4];
    const float* g1  = (const float*)d_in[5];
    const float* be1 = (const float*)d_in[6];
    const float* rm1 = (const float*)d_in[7];
    const float* rv1 = (const float*)d_in[8];
    const float* Wl2 = (const float*)d_in[9];
    const float* bl2 = (const float*)d_in[10];
    const float* Wr2 = (const float*)d_in[11];
    const float* g2  = (const float*)d_in[12];
    const float* be2 = (const float*)d_in[13];
    const float* rm2 = (const float*)d_in[14];
    const float* rv2 = (const float*)d_in[15];
    const float* Wl3 = (const float*)d_in[16];
    const float* bl3 = (const float*)d_in[17];
    const float* Wr3 = (const float*)d_in[18];

    const int N = in_sizes[0] / 128;
    const int E = in_sizes[1] / 2;
    const int* src = ei;
    const int* dst = ei + E;

    // workspace layout
    char* w = (char*)d_ws;
    auto au = [](size_t v) { return (v + 1023) & ~(size_t)1023; };
    size_t off = 0;
    int*            cntS   = (int*)(w + off);            off += (size_t)N * 4;      // cntS+cntD contiguous:
    int*            cntD   = (int*)(w + off);            off += au((size_t)N * 4);  //   one memset covers both
    float*          invdeg = (float*)(w + off);          off += au((size_t)N * 4);
    int*            bucketS= (int*)(w + off);            off += au((size_t)N * CAP * 4);
    unsigned short* xb     = (unsigned short*)(w + off); off += au((size_t)N * 128 * 2);
    unsigned short* hb     = (unsigned short*)(w + off); off += au((size_t)N * 128 * 2);
    unsigned short* hb2    = (unsigned short*)(w + off); off += au((size_t)N * 128 * 2);
    unsigned short* t3b    = (unsigned short*)(w + off); off += au((size_t)N * 64 * 2);
    unsigned short* acc1   = (unsigned short*)(w + off); off += (size_t)N * 128 * 2;  // acc1..acc3 contiguous:
    unsigned short* acc2   = (unsigned short*)(w + off); off += (size_t)N * 128 * 2;  //   one memset covers all
    unsigned short* acc3   = (unsigned short*)(w + off); off += au((size_t)N * 64 * 2);
    unsigned short* Wp[6];
    Wp[0] = (unsigned short*)(w + off); off += au(128 * 128 * 2);  // Wl1
    Wp[1] = (unsigned short*)(w + off); off += au(128 * 128 * 2);  // Wr1
    Wp[2] = (unsigned short*)(w + off); off += au(128 * 128 * 2);  // Wl2
    Wp[3] = (unsigned short*)(w + off); off += au(128 * 128 * 2);  // Wr2
    Wp[4] = (unsigned short*)(w + off); off += au(128 * 64 * 2);   // Wl3
    Wp[5] = (unsigned short*)(w + off); off += au(128 * 64 * 2);   // Wr3
    float* P = (float*)(w + off); off += 2048;
    (void)ws_size; (void)n_in;

    hipMemsetAsync(cntS, 0, (size_t)N * 8, stream);                       // cntS + cntD
    hipMemsetAsync(acc1, 0, (size_t)N * (128 + 128 + 64) * 2, stream);    // acc1 + acc2 + acc3
    k_csr<<<(E + 255) / 256, 256, 0, stream>>>(src, dst, E, cntS, cntD, bucketS);
    k_invdeg<<<(N + 255) / 256, 256, 0, stream>>>(cntD, invdeg, N);
    dim3 pg(64, 7);
    k_prepack<<<pg, 256, 0, stream>>>(Wl1, Wr1, Wl2, Wr2, Wl3, Wr3,
                                      Wp[0], Wp[1], Wp[2], Wp[3], Wp[4], Wp[5],
                                      g1, be1, rm1, rv1, bl1, g2, be2, rm2, rv2, bl2, P);
    k_cvt<<<((N * 128 / 4) + 255) / 256, 256, 0, stream>>>(x, xb, N * 128 / 4);

    const int pushGrid  = ((size_t)N * 64 + 255) / 256;   // one wave per src node
    const int denseGrid = (N + 31) / 32;

    // layer 1: hb = relu(bn(mean-agg(x)@Wl1 + bl1 + x@Wr1))
    k_push<64><<<pushGrid, 256, 0, stream>>>((const unsigned*)xb, cntS, bucketS, invdeg, (unsigned*)acc1, N);
    k_dense<false><<<denseGrid, 256, 0, stream>>>(acc1, xb, Wp[0], Wp[1], P, P + 128, hb, nullptr, nullptr, N);

    // layer 2: hb2 = relu(bn(mean-agg(hb)@Wl2 + bl2 + hb@Wr2)); t3b = hb2@Wl3
    k_push<64><<<pushGrid, 256, 0, stream>>>((const unsigned*)hb, cntS, bucketS, invdeg, (unsigned*)acc2, N);
    k_dense<true><<<denseGrid, 256, 0, stream>>>(acc2, hb, Wp[2], Wp[3], P + 256, P + 384, hb2, Wp[4], t3b, N);

    // layer 3: out = mean-agg(t3b) + hb2@Wr3 + bl3
    k_push<32><<<pushGrid, 256, 0, stream>>>((const unsigned*)t3b, cntS, bucketS, invdeg, (unsigned*)acc3, N);
    k_final<<<denseGrid, 256, 0, stream>>>(hb2, acc3, Wp[5], bl3, (float*)d_out, N);
}

// Round 10
// 323.667 us; speedup vs baseline: 1.8450x; 1.8450x over previous
//
#include <hip/hip_runtime.h>

#define CAP 48

typedef short    s8v __attribute__((ext_vector_type(8)));
typedef float    f4v __attribute__((ext_vector_type(4)));
typedef unsigned u4v __attribute__((ext_vector_type(4)));

__device__ __forceinline__ unsigned short f2bf(float f) {
    unsigned u = __float_as_uint(f);
    u += 0x7FFFu + ((u >> 16) & 1u);      // RNE
    return (unsigned short)(u >> 16);
}
__device__ __forceinline__ float bflo(unsigned v) { return __uint_as_float(v << 16); }
__device__ __forceinline__ float bfhi(unsigned v) { return __uint_as_float(v & 0xffff0000u); }

#define ACC8(v)  do { a[0]+=bflo((v).x); a[1]+=bfhi((v).x); a[2]+=bflo((v).y); a[3]+=bfhi((v).y); \
                      a[4]+=bflo((v).z); a[5]+=bfhi((v).z); a[6]+=bflo((v).w); a[7]+=bfhi((v).w); } while(0)

// non-temporal gather load: no L1 allocation -> gather concurrency not bounded
// by TCP MSHRs (R7 A/B: this is the ONLY change vs R7). ext_vector type because
// __builtin_nontemporal_load rejects HIP_vector_type pointers.
__device__ __forceinline__ u4v ntload(const unsigned* p) {
    return __builtin_nontemporal_load((const u4v*)p);
}

// ---- build bucketed CSR (by dst) -------------------------------------------
__global__ __launch_bounds__(256) void k_bucket(const int* __restrict__ src, const int* __restrict__ dst,
                                                int E, int* __restrict__ cnt, int* __restrict__ bucket) {
    int e = blockIdx.x * 256 + threadIdx.x;
    if (e < E) {
        int d = dst[e];
        int slot = atomicAdd(&cnt[d], 1);
        if (slot < CAP) bucket[(size_t)d * CAP + slot] = src[e];
    }
}

// ---- merged: pack 6 weights (y=0..5) + BN fold + zero-row init (y=6) -------
__global__ __launch_bounds__(256) void k_prepack(const float* W0, const float* W1, const float* W2,
                                                 const float* W3, const float* W4, const float* W5,
                                                 unsigned short* P0, unsigned short* P1, unsigned short* P2,
                                                 unsigned short* P3, unsigned short* P4, unsigned short* P5,
                                                 const float* g1, const float* be1, const float* rm1, const float* rv1, const float* bl1,
                                                 const float* g2, const float* be2, const float* rm2, const float* rv2, const float* bl2,
                                                 float* P,
                                                 unsigned short* xb, unsigned short* hb, unsigned short* hb2,
                                                 unsigned short* t3b, int N) {
    if (blockIdx.y == 6) {
        if (blockIdx.x == 0) {
            int i = threadIdx.x;
            if (i < 128) {
                float s1 = g1[i] * rsqrtf(rv1[i] + 1e-5f);
                P[i]       = s1;
                P[128 + i] = (bl1[i] - rm1[i]) * s1 + be1[i];
                float s2 = g2[i] * rsqrtf(rv2[i] + 1e-5f);
                P[256 + i] = s2;
                P[384 + i] = (bl2[i] - rm2[i]) * s2 + be2[i];
                // zero row N of each feature buffer (gather padding target)
                xb [(size_t)N * 128 + i] = 0;
                hb [(size_t)N * 128 + i] = 0;
                hb2[(size_t)N * 128 + i] = 0;
                if (i < 64) t3b[(size_t)N * 64 + i] = 0;
            }
        }
        return;
    }
    const float* W; unsigned short* Pk; int JD;
    switch (blockIdx.y) {
        case 0: W = W0; Pk = P0; JD = 128; break;
        case 1: W = W1; Pk = P1; JD = 128; break;
        case 2: W = W2; Pk = P2; JD = 128; break;
        case 3: W = W3; Pk = P3; JD = 128; break;
        case 4: W = W4; Pk = P4; JD = 64;  break;
        default:W = W5; Pk = P5; JD = 64;  break;
    }
    int o = blockIdx.x * 256 + threadIdx.x;
    if (o >= 128 * JD) return;
    int j    = o & 7;
    int lane = (o >> 3) & 63;
    int t    = o >> 9;
    int nt   = t % (JD / 16);
    int kt   = t / (JD / 16);
    int k = kt * 32 + (lane >> 4) * 8 + j;
    int n = nt * 16 + (lane & 15);
    Pk[o] = f2bf(W[(size_t)k * JD + n]);
}

// ---- fp32 -> bf16 row-major convert ----------------------------------------
__global__ __launch_bounds__(256) void k_cvt(const float* __restrict__ in, unsigned short* __restrict__ out, int n4) {
    int i = blockIdx.x * 256 + threadIdx.x;
    if (i < n4) {
        float4 v = ((const float4*)in)[i];
        ushort4 o;
        o.x = f2bf(v.x); o.y = f2bf(v.y); o.z = f2bf(v.z); o.w = f2bf(v.w);
        ((ushort4*)out)[i] = o;
    }
}

// ---- fused SAGE layer: gather-mean -> LDS, dual MFMA, BN+ReLU epilogue -----
// block = 32 nodes, 4 waves. Gather: quarter-wave per node (16 lanes x 16B),
// 2 serial slots/wave, branch-free unroll-8 rounds via zero-row clamping.
template<bool T3>
__global__ __launch_bounds__(256) void k_fused(const unsigned short* __restrict__ feat,
                                               const int* __restrict__ cnt, const int* __restrict__ bucket,
                                               const unsigned short* __restrict__ Bl, const unsigned short* __restrict__ Br,
                                               const float* __restrict__ scale, const float* __restrict__ shift,
                                               unsigned short* __restrict__ out,
                                               const unsigned short* __restrict__ W3p, unsigned short* __restrict__ t3,
                                               int n) {
    __shared__ unsigned short sA[32 * 136];
    __shared__ unsigned short sH[T3 ? 32 * 136 : 8];
    const int tid  = threadIdx.x;
    const int wave = tid >> 6;
    const int lane = tid & 63;
    const int nb0  = blockIdx.x * 32;
    if (nb0 >= n) return;

    // ---- phase 1: gather-mean ----------------------------------------------
    {
        const int q4   = lane >> 4;
        const int li   = lane & 15;
        const int base = q4 << 4;
        const unsigned* inp = (const unsigned*)feat;   // row = 64 uints; lane takes 4 (16B)
        int rows[2], cs[2], idxs[2];
        #pragma unroll
        for (int t = 0; t < 2; t++) {
            rows[t] = wave * 8 + t * 4 + q4;
            int node = nb0 + rows[t];
            bool ok = node < n;
            int c = ok ? cnt[node] : 0; if (c > CAP) c = CAP;
            cs[t] = c;
            idxs[t] = (ok && li < c) ? bucket[(size_t)node * CAP + li] : n;  // n = zero row
        }
        #pragma unroll
        for (int t = 0; t < 2; t++) {
            const int c = cs[t];
            float a[8] = {0.f, 0.f, 0.f, 0.f, 0.f, 0.f, 0.f, 0.f};
            if (c > 0) {
                #pragma unroll
                for (int u = 0; u < 8; u++) {
                    int idx = __shfl(idxs[t], base + u);        // >=c lanes hold n (zero row)
                    u4v v = ntload(inp + (size_t)idx * 64 + li * 4);
                    ACC8(v);
                }
            }
            if (c > 8) {
                #pragma unroll
                for (int u = 8; u < 16; u++) {
                    int idx = __shfl(idxs[t], base + u);
                    u4v v = ntload(inp + (size_t)idx * 64 + li * 4);
                    ACC8(v);
                }
            }
            const int node = nb0 + rows[t];
            for (int s = 16; s < c; s++) {                      // deg>16 (rare)
                int idx = bucket[(size_t)node * CAP + s];
                u4v v = ntload(inp + (size_t)idx * 64 + li * 4);
                ACC8(v);
            }
            if (node < n) {
                float iv = 1.0f / fmaxf((float)c, 1.0f);
                uint4 o;
                o.x = (unsigned)f2bf(a[0] * iv) | ((unsigned)f2bf(a[1] * iv) << 16);
                o.y = (unsigned)f2bf(a[2] * iv) | ((unsigned)f2bf(a[3] * iv) << 16);
                o.z = (unsigned)f2bf(a[4] * iv) | ((unsigned)f2bf(a[5] * iv) << 16);
                o.w = (unsigned)f2bf(a[6] * iv) | ((unsigned)f2bf(a[7] * iv) << 16);
                *(uint4*)(sA + rows[t] * 136 + li * 8) = o;
            }
        }
    }
    __syncthreads();

    // ---- phase 2: dual MFMA, wave = 32 rows x 32 cols (nt0 = wave*2) --------
    const int m = lane & 15;
    const int q = lane >> 4;
    const int nt0 = wave * 2;
    const int rg0 = min(nb0 + m,      n - 1);
    const int rg1 = min(nb0 + 16 + m, n - 1);

    f4v acc[2][2];
    #pragma unroll
    for (int mt = 0; mt < 2; mt++)
        #pragma unroll
        for (int c = 0; c < 2; c++) {
            acc[mt][c][0] = 0.f; acc[mt][c][1] = 0.f; acc[mt][c][2] = 0.f; acc[mt][c][3] = 0.f;
        }

    #pragma unroll
    for (int kt = 0; kt < 4; kt++) {
        const int ko = kt * 32 + q * 8;
        s8v a0 = *(const s8v*)(sA + m * 136 + ko);                // agg side (LDS)
        s8v a1 = *(const s8v*)(sA + (16 + m) * 136 + ko);
        s8v a0d = *(const s8v*)(feat + (size_t)rg0 * 128 + ko);   // root side (global)
        s8v a1d = *(const s8v*)(feat + (size_t)rg1 * 128 + ko);
        #pragma unroll
        for (int c = 0; c < 2; c++) {
            s8v b  = *(const s8v*)(Bl + ((size_t)(kt * 8 + nt0 + c) * 64 + lane) * 8);
            acc[0][c] = __builtin_amdgcn_mfma_f32_16x16x32_bf16(a0, b, acc[0][c], 0, 0, 0);
            acc[1][c] = __builtin_amdgcn_mfma_f32_16x16x32_bf16(a1, b, acc[1][c], 0, 0, 0);
            s8v b2 = *(const s8v*)(Br + ((size_t)(kt * 8 + nt0 + c) * 64 + lane) * 8);
            acc[0][c] = __builtin_amdgcn_mfma_f32_16x16x32_bf16(a0d, b2, acc[0][c], 0, 0, 0);
            acc[1][c] = __builtin_amdgcn_mfma_f32_16x16x32_bf16(a1d, b2, acc[1][c], 0, 0, 0);
        }
    }

    // ---- epilogue: BN+ReLU, write bf16 (and stash tile for t3) -------------
    float scv[2], shv[2];
    #pragma unroll
    for (int c = 0; c < 2; c++) {
        int col = (nt0 + c) * 16 + m;
        scv[c] = scale[col]; shv[c] = shift[col];
    }
    #pragma unroll
    for (int mt = 0; mt < 2; mt++) {
        #pragma unroll
        for (int reg = 0; reg < 4; reg++) {
            int rloc = mt * 16 + q * 4 + reg;
            int row  = nb0 + rloc;
            if (row < n) {
                #pragma unroll
                for (int c = 0; c < 2; c++) {
                    int col = (nt0 + c) * 16 + m;
                    float v = fmaxf(acc[mt][c][reg] * scv[c] + shv[c], 0.f);
                    unsigned short u = f2bf(v);
                    out[(size_t)row * 128 + col] = u;
                    if constexpr (T3) sH[rloc * 136 + col] = u;
                }
            }
        }
    }

    // ---- phase 3 (layer 2 only): t3 = hb2_tile @ Wl3, wave = 16 cols -------
    if constexpr (T3) {
        __syncthreads();
        f4v a3c[2];
        #pragma unroll
        for (int mt = 0; mt < 2; mt++) { a3c[mt][0] = 0.f; a3c[mt][1] = 0.f; a3c[mt][2] = 0.f; a3c[mt][3] = 0.f; }
        #pragma unroll
        for (int kt = 0; kt < 4; kt++) {
            const int ko = kt * 32 + q * 8;
            s8v a0 = *(const s8v*)(sH + m * 136 + ko);
            s8v a1 = *(const s8v*)(sH + (16 + m) * 136 + ko);
            s8v b  = *(const s8v*)(W3p + ((size_t)(kt * 4 + wave) * 64 + lane) * 8);
            a3c[0] = __builtin_amdgcn_mfma_f32_16x16x32_bf16(a0, b, a3c[0], 0, 0, 0);
            a3c[1] = __builtin_amdgcn_mfma_f32_16x16x32_bf16(a1, b, a3c[1], 0, 0, 0);
        }
        #pragma unroll
        for (int mt = 0; mt < 2; mt++) {
            #pragma unroll
            for (int reg = 0; reg < 4; reg++) {
                int row = nb0 + mt * 16 + q * 4 + reg;
                if (row < n) t3[(size_t)row * 64 + wave * 16 + m] = f2bf(a3c[mt][reg]);
            }
        }
    }
}

// ---- fused layer 3: gather-mean(t3) + hb2@Wr3 + bias -----------------------
// block = 32 nodes, 4 waves. Gather: eighth-wave per node (8 lanes x 16B),
// 8 nodes concurrent per wave, 1 slot, branch-free unroll-8 rounds.
__global__ __launch_bounds__(256) void k_final(const unsigned short* __restrict__ hb2,
                                               const unsigned short* __restrict__ t3,
                                               const int* __restrict__ cnt, const int* __restrict__ bucket,
                                               const unsigned short* __restrict__ Bp, const float* __restrict__ bias,
                                               float* __restrict__ outf, int n) {
    __shared__ float sG[32 * 68];   // fp32 agg tile, stride 68 floats
    const int tid  = threadIdx.x;
    const int wave = tid >> 6;
    const int lane = tid & 63;
    const int nb0  = blockIdx.x * 32;
    if (nb0 >= n) return;

    // ---- phase 1: gather-mean ----------------------------------------------
    {
        const int e8   = lane >> 3;
        const int li   = lane & 7;
        const int base = e8 << 3;
        const unsigned* inp = (const unsigned*)t3;     // row = 32 uints; lane takes 4 (16B)
        const int row  = wave * 8 + e8;
        const int node = nb0 + row;
        const bool ok  = node < n;
        int c = ok ? cnt[node] : 0; if (c > CAP) c = CAP;
        int idx1 = (ok && li < c)     ? bucket[(size_t)node * CAP + li]     : n;
        int idx2 = (ok && li + 8 < c) ? bucket[(size_t)node * CAP + li + 8] : n;
        float a[8] = {0.f, 0.f, 0.f, 0.f, 0.f, 0.f, 0.f, 0.f};
        if (c > 0) {
            #pragma unroll
            for (int u = 0; u < 8; u++) {
                int idx = __shfl(idx1, base + u);
                u4v v = ntload(inp + (size_t)idx * 32 + li * 4);
                ACC8(v);
            }
        }
        if (c > 8) {
            #pragma unroll
            for (int u = 0; u < 8; u++) {
                int idx = __shfl(idx2, base + u);
                u4v v = ntload(inp + (size_t)idx * 32 + li * 4);
                ACC8(v);
            }
        }
        for (int s = 16; s < c; s++) {             // deg>16 (rare)
            int idx = bucket[(size_t)node * CAP + s];
            u4v v = ntload(inp + (size_t)idx * 32 + li * 4);
            ACC8(v);
        }
        if (ok) {
            float iv = 1.0f / fmaxf((float)c, 1.0f);
            float4 o1; o1.x = a[0] * iv; o1.y = a[1] * iv; o1.z = a[2] * iv; o1.w = a[3] * iv;
            float4 o2; o2.x = a[4] * iv; o2.y = a[5] * iv; o2.z = a[6] * iv; o2.w = a[7] * iv;
            *(float4*)(sG + row * 68 + li * 8)     = o1;
            *(float4*)(sG + row * 68 + li * 8 + 4) = o2;
        }
    }
    __syncthreads();

    // ---- phase 2: out = hb2 @ Wr3 + agg + bias ------------------------------
    const int m = lane & 15;
    const int q = lane >> 4;
    const int rg0 = min(nb0 + m,      n - 1);
    const int rg1 = min(nb0 + 16 + m, n - 1);

    f4v acc[2];
    #pragma unroll
    for (int mt = 0; mt < 2; mt++) { acc[mt][0] = 0.f; acc[mt][1] = 0.f; acc[mt][2] = 0.f; acc[mt][3] = 0.f; }

    #pragma unroll
    for (int kt = 0; kt < 4; kt++) {
        const int ko = kt * 32 + q * 8;
        s8v a0 = *(const s8v*)(hb2 + (size_t)rg0 * 128 + ko);
        s8v a1 = *(const s8v*)(hb2 + (size_t)rg1 * 128 + ko);
        s8v b  = *(const s8v*)(Bp + ((size_t)(kt * 4 + wave) * 64 + lane) * 8);
        acc[0] = __builtin_amdgcn_mfma_f32_16x16x32_bf16(a0, b, acc[0], 0, 0, 0);
        acc[1] = __builtin_amdgcn_mfma_f32_16x16x32_bf16(a1, b, acc[1], 0, 0, 0);
    }

    const int col = wave * 16 + m;
    const float bv = bias[col];
    #pragma unroll
    for (int mt = 0; mt < 2; mt++) {
        #pragma unroll
        for (int reg = 0; reg < 4; reg++) {
            int rloc = mt * 16 + q * 4 + reg;
            int row  = nb0 + rloc;
            if (row < n) outf[(size_t)row * 64 + col] = acc[mt][reg] + sG[rloc * 68 + col] + bv;
        }
    }
}

extern "C" void kernel_launch(void* const* d_in, const int* in_sizes, int n_in,
                              void* d_out, int out_size, void* d_ws, size_t ws_size,
                              hipStream_t stream) {
    const float* x   = (const float*)d_in[0];
    const int*   ei  = (const int*)d_in[1];
    const float* Wl1 = (const float*)d_in[2];
    const float* bl1 = (const float*)d_in[3];
    const float* Wr1 = (const float*)d_in[4];
    const float* g1  = (const float*)d_in[5];
    const float* be1 = (const float*)d_in[6];
    const float* rm1 = (const float*)d_in[7];
    const float* rv1 = (const float*)d_in[8];
    const float* Wl2 = (const float*)d_in[9];
    const float* bl2 = (const float*)d_in[10];
    const float* Wr2 = (const float*)d_in[11];
    const float* g2  = (const float*)d_in[12];
    const float* be2 = (const float*)d_in[13];
    const float* rm2 = (const float*)d_in[14];
    const float* rv2 = (const float*)d_in[15];
    const float* Wl3 = (const float*)d_in[16];
    const float* bl3 = (const float*)d_in[17];
    const float* Wr3 = (const float*)d_in[18];

    const int N = in_sizes[0] / 128;
    const int E = in_sizes[1] / 2;
    const int* src = ei;
    const int* dst = ei + E;

    // workspace layout (feature buffers have N+1 rows; row N is the zero row)
    char* w = (char*)d_ws;
    auto au = [](size_t v) { return (v + 1023) & ~(size_t)1023; };
    size_t off = 0;
    int*            cnt    = (int*)(w + off);            off += au((size_t)N * 4);
    int*            bucket = (int*)(w + off);            off += au((size_t)N * CAP * 4);
    unsigned short* xb     = (unsigned short*)(w + off); off += au((size_t)(N + 1) * 128 * 2);
    unsigned short* hb     = (unsigned short*)(w + off); off += au((size_t)(N + 1) * 128 * 2);
    unsigned short* hb2    = (unsigned short*)(w + off); off += au((size_t)(N + 1) * 128 * 2);
    unsigned short* t3b    = (unsigned short*)(w + off); off += au((size_t)(N + 1) * 64 * 2);
    unsigned short* Wp[6];
    Wp[0] = (unsigned short*)(w + off); off += au(128 * 128 * 2);  // Wl1
    Wp[1] = (unsigned short*)(w + off); off += au(128 * 128 * 2);  // Wr1
    Wp[2] = (unsigned short*)(w + off); off += au(128 * 128 * 2);  // Wl2
    Wp[3] = (unsigned short*)(w + off); off += au(128 * 128 * 2);  // Wr2
    Wp[4] = (unsigned short*)(w + off); off += au(128 * 64 * 2);   // Wl3
    Wp[5] = (unsigned short*)(w + off); off += au(128 * 64 * 2);   // Wr3
    float* P = (float*)(w + off); off += 2048;
    (void)ws_size; (void)n_in;

    (void)hipMemsetAsync(cnt, 0, (size_t)N * 4, stream);
    k_bucket<<<(E + 255) / 256, 256, 0, stream>>>(src, dst, E, cnt, bucket);
    dim3 pg(64, 7);
    k_prepack<<<pg, 256, 0, stream>>>(Wl1, Wr1, Wl2, Wr2, Wl3, Wr3,
                                      Wp[0], Wp[1], Wp[2], Wp[3], Wp[4], Wp[5],
                                      g1, be1, rm1, rv1, bl1, g2, be2, rm2, rv2, bl2, P,
                                      xb, hb, hb2, t3b, N);
    k_cvt<<<((N * 128 / 4) + 255) / 256, 256, 0, stream>>>(x, xb, N * 128 / 4);

    const int grid = (N + 31) / 32;

    // layer 1: hb = relu(bn(agg(x)@Wl1 + bl1 + x@Wr1))
    k_fused<false><<<grid, 256, 0, stream>>>(xb, cnt, bucket, Wp[0], Wp[1],
                                             P, P + 128, hb, nullptr, nullptr, N);
    // layer 2: hb2 = relu(bn(agg(hb)@Wl2 + bl2 + hb@Wr2)); t3b = hb2@Wl3
    k_fused<true><<<grid, 256, 0, stream>>>(hb, cnt, bucket, Wp[2], Wp[3],
                                            P + 256, P + 384, hb2, Wp[4], t3b, N);
    // layer 3: out = agg(t3b) + hb2@Wr3 + bl3
    k_final<<<grid, 256, 0, stream>>>(hb2, t3b, cnt, bucket, Wp[5], bl3, (float*)d_out, N);
}

// Round 11
// 297.226 us; speedup vs baseline: 2.0091x; 1.0890x over previous
//
#include <hip/hip_runtime.h>

#define CAP 48

typedef short  s8v  __attribute__((ext_vector_type(8)));
typedef float  f4v  __attribute__((ext_vector_type(4)));

__device__ __forceinline__ unsigned short f2bf(float f) {
    unsigned u = __float_as_uint(f);
    u += 0x7FFFu + ((u >> 16) & 1u);      // RNE
    return (unsigned short)(u >> 16);
}
__device__ __forceinline__ float bflo(unsigned v) { return __uint_as_float(v << 16); }
__device__ __forceinline__ float bfhi(unsigned v) { return __uint_as_float(v & 0xffff0000u); }

#define ACC8(v)  do { a[0]+=bflo((v).x); a[1]+=bfhi((v).x); a[2]+=bflo((v).y); a[3]+=bfhi((v).y); \
                      a[4]+=bflo((v).z); a[5]+=bfhi((v).z); a[6]+=bflo((v).w); a[7]+=bfhi((v).w); } while(0)

// ---- build bucketed CSR (by dst): dense 16-slot array + overflow ------------
__global__ __launch_bounds__(256) void k_bucket(const int* __restrict__ src, const int* __restrict__ dst,
                                                int E, int* __restrict__ cnt,
                                                int* __restrict__ b16, int* __restrict__ bov) {
    int e = blockIdx.x * 256 + threadIdx.x;
    if (e < E) {
        int d = dst[e];
        int slot = atomicAdd(&cnt[d], 1);
        if (slot < 16)       b16[(size_t)d * 16 + slot] = src[e];
        else if (slot < CAP) bov[(size_t)d * (CAP - 16) + slot - 16] = src[e];
    }
}

// ---- merged: pack 6 weights (y=0..5) + BN fold + zero-row init (y=6) -------
__global__ __launch_bounds__(256) void k_prepack(const float* W0, const float* W1, const float* W2,
                                                 const float* W3, const float* W4, const float* W5,
                                                 unsigned short* P0, unsigned short* P1, unsigned short* P2,
                                                 unsigned short* P3, unsigned short* P4, unsigned short* P5,
                                                 const float* g1, const float* be1, const float* rm1, const float* rv1, const float* bl1,
                                                 const float* g2, const float* be2, const float* rm2, const float* rv2, const float* bl2,
                                                 float* P,
                                                 unsigned short* xb, unsigned short* hb, unsigned short* hb2,
                                                 unsigned short* t3b, int N) {
    if (blockIdx.y == 6) {
        if (blockIdx.x == 0) {
            int i = threadIdx.x;
            if (i < 128) {
                float s1 = g1[i] * rsqrtf(rv1[i] + 1e-5f);
                P[i]       = s1;
                P[128 + i] = (bl1[i] - rm1[i]) * s1 + be1[i];
                float s2 = g2[i] * rsqrtf(rv2[i] + 1e-5f);
                P[256 + i] = s2;
                P[384 + i] = (bl2[i] - rm2[i]) * s2 + be2[i];
                // zero row N of each feature buffer (gather padding target)
                xb [(size_t)N * 128 + i] = 0;
                hb [(size_t)N * 128 + i] = 0;
                hb2[(size_t)N * 128 + i] = 0;
                if (i < 64) t3b[(size_t)N * 64 + i] = 0;
            }
        }
        return;
    }
    const float* W; unsigned short* Pk; int JD;
    switch (blockIdx.y) {
        case 0: W = W0; Pk = P0; JD = 128; break;
        case 1: W = W1; Pk = P1; JD = 128; break;
        case 2: W = W2; Pk = P2; JD = 128; break;
        case 3: W = W3; Pk = P3; JD = 128; break;
        case 4: W = W4; Pk = P4; JD = 64;  break;
        default:W = W5; Pk = P5; JD = 64;  break;
    }
    int o = blockIdx.x * 256 + threadIdx.x;
    if (o >= 128 * JD) return;
    int j    = o & 7;
    int lane = (o >> 3) & 63;
    int t    = o >> 9;
    int nt   = t % (JD / 16);
    int kt   = t / (JD / 16);
    int k = kt * 32 + (lane >> 4) * 8 + j;
    int n = nt * 16 + (lane & 15);
    Pk[o] = f2bf(W[(size_t)k * JD + n]);
}

// ---- fp32 -> bf16 row-major convert ----------------------------------------
__global__ __launch_bounds__(256) void k_cvt(const float* __restrict__ in, unsigned short* __restrict__ out, int n4) {
    int i = blockIdx.x * 256 + threadIdx.x;
    if (i < n4) {
        float4 v = ((const float4*)in)[i];
        ushort4 o;
        o.x = f2bf(v.x); o.y = f2bf(v.y); o.z = f2bf(v.z); o.w = f2bf(v.w);
        ((ushort4*)out)[i] = o;
    }
}

// ---- fused SAGE layer: gather-mean -> LDS, dual MFMA, BN+ReLU epilogue -----
// block = 32 nodes, 4 waves. Gather: quarter-wave per node (16 lanes x uint4),
// dense bucket16 index rows (64B), zero-row clamp, unroll-8 rounds.
template<bool T3>
__global__ __launch_bounds__(256) void k_fused(const unsigned short* __restrict__ feat,
                                               const int* __restrict__ cnt, const int* __restrict__ b16,
                                               const int* __restrict__ bov,
                                               const unsigned short* __restrict__ Bl, const unsigned short* __restrict__ Br,
                                               const float* __restrict__ scale, const float* __restrict__ shift,
                                               unsigned short* __restrict__ out,
                                               const unsigned short* __restrict__ W3p, unsigned short* __restrict__ t3,
                                               int n) {
    __shared__ unsigned short sA[32 * 136];
    __shared__ unsigned short sH[T3 ? 32 * 136 : 8];
    const int tid  = threadIdx.x;
    const int wave = tid >> 6;
    const int lane = tid & 63;
    const int nb0  = blockIdx.x * 32;
    if (nb0 >= n) return;

    // ---- phase 1: gather-mean ----------------------------------------------
    {
        const int q4   = lane >> 4;
        const int li   = lane & 15;
        const int base = q4 << 4;
        const uint4* inp = (const uint4*)feat;     // 256B row = 16 x uint4
        int rows[2], cs[2], idxs[2];
        #pragma unroll
        for (int t = 0; t < 2; t++) {
            rows[t] = wave * 8 + t * 4 + q4;
            int node = nb0 + rows[t];
            bool ok = node < n;
            int c = ok ? cnt[node] : 0; if (c > CAP) c = CAP;
            cs[t] = c;
            idxs[t] = (ok && li < c) ? b16[(size_t)node * 16 + li] : n;  // n = zero row
        }
        #pragma unroll
        for (int t = 0; t < 2; t++) {
            const int c = cs[t];
            float a[8] = {0.f, 0.f, 0.f, 0.f, 0.f, 0.f, 0.f, 0.f};
            if (c > 0) {
                #pragma unroll
                for (int u = 0; u < 8; u++) {
                    int idx = __shfl(idxs[t], base + u);        // >=c lanes hold n (zero row)
                    uint4 v = inp[(size_t)idx * 16 + li];
                    ACC8(v);
                }
            }
            if (c > 8) {
                #pragma unroll
                for (int u = 8; u < 16; u++) {
                    int idx = __shfl(idxs[t], base + u);
                    uint4 v = inp[(size_t)idx * 16 + li];
                    ACC8(v);
                }
            }
            const int node = nb0 + rows[t];
            for (int s = 16; s < c; s++) {                      // deg>16 (rare)
                int idx = bov[(size_t)node * (CAP - 16) + s - 16];
                uint4 v = inp[(size_t)idx * 16 + li];
                ACC8(v);
            }
            if (node < n) {
                float iv = 1.0f / fmaxf((float)c, 1.0f);
                uint4 o;
                o.x = (unsigned)f2bf(a[0] * iv) | ((unsigned)f2bf(a[1] * iv) << 16);
                o.y = (unsigned)f2bf(a[2] * iv) | ((unsigned)f2bf(a[3] * iv) << 16);
                o.z = (unsigned)f2bf(a[4] * iv) | ((unsigned)f2bf(a[5] * iv) << 16);
                o.w = (unsigned)f2bf(a[6] * iv) | ((unsigned)f2bf(a[7] * iv) << 16);
                *(uint4*)(sA + rows[t] * 136 + li * 8) = o;
            }
        }
    }
    __syncthreads();

    // ---- phase 2: dual MFMA, wave = 32 rows x 32 cols (nt0 = wave*2) --------
    const int m = lane & 15;
    const int q = lane >> 4;
    const int nt0 = wave * 2;
    const int rg0 = min(nb0 + m,      n - 1);
    const int rg1 = min(nb0 + 16 + m, n - 1);

    f4v acc[2][2];
    #pragma unroll
    for (int mt = 0; mt < 2; mt++)
        #pragma unroll
        for (int c = 0; c < 2; c++) {
            acc[mt][c][0] = 0.f; acc[mt][c][1] = 0.f; acc[mt][c][2] = 0.f; acc[mt][c][3] = 0.f;
        }

    #pragma unroll
    for (int kt = 0; kt < 4; kt++) {
        const int ko = kt * 32 + q * 8;
        s8v a0 = *(const s8v*)(sA + m * 136 + ko);                // agg side (LDS)
        s8v a1 = *(const s8v*)(sA + (16 + m) * 136 + ko);
        s8v a0d = *(const s8v*)(feat + (size_t)rg0 * 128 + ko);   // root side (global)
        s8v a1d = *(const s8v*)(feat + (size_t)rg1 * 128 + ko);
        #pragma unroll
        for (int c = 0; c < 2; c++) {
            s8v b  = *(const s8v*)(Bl + ((size_t)(kt * 8 + nt0 + c) * 64 + lane) * 8);
            acc[0][c] = __builtin_amdgcn_mfma_f32_16x16x32_bf16(a0, b, acc[0][c], 0, 0, 0);
            acc[1][c] = __builtin_amdgcn_mfma_f32_16x16x32_bf16(a1, b, acc[1][c], 0, 0, 0);
            s8v b2 = *(const s8v*)(Br + ((size_t)(kt * 8 + nt0 + c) * 64 + lane) * 8);
            acc[0][c] = __builtin_amdgcn_mfma_f32_16x16x32_bf16(a0d, b2, acc[0][c], 0, 0, 0);
            acc[1][c] = __builtin_amdgcn_mfma_f32_16x16x32_bf16(a1d, b2, acc[1][c], 0, 0, 0);
        }
    }

    // ---- epilogue: BN+ReLU, write bf16 (and stash tile for t3) -------------
    float scv[2], shv[2];
    #pragma unroll
    for (int c = 0; c < 2; c++) {
        int col = (nt0 + c) * 16 + m;
        scv[c] = scale[col]; shv[c] = shift[col];
    }
    #pragma unroll
    for (int mt = 0; mt < 2; mt++) {
        #pragma unroll
        for (int reg = 0; reg < 4; reg++) {
            int rloc = mt * 16 + q * 4 + reg;
            int row  = nb0 + rloc;
            if (row < n) {
                #pragma unroll
                for (int c = 0; c < 2; c++) {
                    int col = (nt0 + c) * 16 + m;
                    float v = fmaxf(acc[mt][c][reg] * scv[c] + shv[c], 0.f);
                    unsigned short u = f2bf(v);
                    out[(size_t)row * 128 + col] = u;
                    if constexpr (T3) sH[rloc * 136 + col] = u;
                }
            }
        }
    }

    // ---- phase 3 (layer 2 only): t3 = hb2_tile @ Wl3, wave = 16 cols -------
    if constexpr (T3) {
        __syncthreads();
        f4v a3c[2];
        #pragma unroll
        for (int mt = 0; mt < 2; mt++) { a3c[mt][0] = 0.f; a3c[mt][1] = 0.f; a3c[mt][2] = 0.f; a3c[mt][3] = 0.f; }
        #pragma unroll
        for (int kt = 0; kt < 4; kt++) {
            const int ko = kt * 32 + q * 8;
            s8v a0 = *(const s8v*)(sH + m * 136 + ko);
            s8v a1 = *(const s8v*)(sH + (16 + m) * 136 + ko);
            s8v b  = *(const s8v*)(W3p + ((size_t)(kt * 4 + wave) * 64 + lane) * 8);
            a3c[0] = __builtin_amdgcn_mfma_f32_16x16x32_bf16(a0, b, a3c[0], 0, 0, 0);
            a3c[1] = __builtin_amdgcn_mfma_f32_16x16x32_bf16(a1, b, a3c[1], 0, 0, 0);
        }
        #pragma unroll
        for (int mt = 0; mt < 2; mt++) {
            #pragma unroll
            for (int reg = 0; reg < 4; reg++) {
                int row = nb0 + mt * 16 + q * 4 + reg;
                if (row < n) t3[(size_t)row * 64 + wave * 16 + m] = f2bf(a3c[mt][reg]);
            }
        }
    }
}

// ---- fused layer 3: gather-mean(t3) + hb2@Wr3 + bias -----------------------
// block = 32 nodes, 4 waves. Gather: eighth-wave per node (8 lanes x uint4),
// 8 nodes concurrent per wave, dense bucket16 rows.
__global__ __launch_bounds__(256) void k_final(const unsigned short* __restrict__ hb2,
                                               const unsigned short* __restrict__ t3,
                                               const int* __restrict__ cnt, const int* __restrict__ b16,
                                               const int* __restrict__ bov,
                                               const unsigned short* __restrict__ Bp, const float* __restrict__ bias,
                                               float* __restrict__ outf, int n) {
    __shared__ float sG[32 * 68];   // fp32 agg tile, stride 68 floats
    const int tid  = threadIdx.x;
    const int wave = tid >> 6;
    const int lane = tid & 63;
    const int nb0  = blockIdx.x * 32;
    if (nb0 >= n) return;

    // ---- phase 1: gather-mean ----------------------------------------------
    {
        const int e8   = lane >> 3;
        const int li   = lane & 7;
        const int base = e8 << 3;
        const uint4* inp = (const uint4*)t3;       // 128B row = 8 x uint4
        const int row  = wave * 8 + e8;
        const int node = nb0 + row;
        const bool ok  = node < n;
        int c = ok ? cnt[node] : 0; if (c > CAP) c = CAP;
        int idx1 = (ok && li < c)     ? b16[(size_t)node * 16 + li]     : n;
        int idx2 = (ok && li + 8 < c) ? b16[(size_t)node * 16 + li + 8] : n;
        float a[8] = {0.f, 0.f, 0.f, 0.f, 0.f, 0.f, 0.f, 0.f};
        if (c > 0) {
            #pragma unroll
            for (int u = 0; u < 8; u++) {
                int idx = __shfl(idx1, base + u);
                uint4 v = inp[(size_t)idx * 8 + li];
                ACC8(v);
            }
        }
        if (c > 8) {
            #pragma unroll
            for (int u = 0; u < 8; u++) {
                int idx = __shfl(idx2, base + u);
                uint4 v = inp[(size_t)idx * 8 + li];
                ACC8(v);
            }
        }
        for (int s = 16; s < c; s++) {             // deg>16 (rare)
            int idx = bov[(size_t)node * (CAP - 16) + s - 16];
            uint4 v = inp[(size_t)idx * 8 + li];
            ACC8(v);
        }
        if (ok) {
            float iv = 1.0f / fmaxf((float)c, 1.0f);
            float4 o1; o1.x = a[0] * iv; o1.y = a[1] * iv; o1.z = a[2] * iv; o1.w = a[3] * iv;
            float4 o2; o2.x = a[4] * iv; o2.y = a[5] * iv; o2.z = a[6] * iv; o2.w = a[7] * iv;
            *(float4*)(sG + row * 68 + li * 8)     = o1;
            *(float4*)(sG + row * 68 + li * 8 + 4) = o2;
        }
    }
    __syncthreads();

    // ---- phase 2: out = hb2 @ Wr3 + agg + bias ------------------------------
    const int m = lane & 15;
    const int q = lane >> 4;
    const int rg0 = min(nb0 + m,      n - 1);
    const int rg1 = min(nb0 + 16 + m, n - 1);

    f4v acc[2];
    #pragma unroll
    for (int mt = 0; mt < 2; mt++) { acc[mt][0] = 0.f; acc[mt][1] = 0.f; acc[mt][2] = 0.f; acc[mt][3] = 0.f; }

    #pragma unroll
    for (int kt = 0; kt < 4; kt++) {
        const int ko = kt * 32 + q * 8;
        s8v a0 = *(const s8v*)(hb2 + (size_t)rg0 * 128 + ko);
        s8v a1 = *(const s8v*)(hb2 + (size_t)rg1 * 128 + ko);
        s8v b  = *(const s8v*)(Bp + ((size_t)(kt * 4 + wave) * 64 + lane) * 8);
        acc[0] = __builtin_amdgcn_mfma_f32_16x16x32_bf16(a0, b, acc[0], 0, 0, 0);
        acc[1] = __builtin_amdgcn_mfma_f32_16x16x32_bf16(a1, b, acc[1], 0, 0, 0);
    }

    const int col = wave * 16 + m;
    const float bv = bias[col];
    #pragma unroll
    for (int mt = 0; mt < 2; mt++) {
        #pragma unroll
        for (int reg = 0; reg < 4; reg++) {
            int rloc = mt * 16 + q * 4 + reg;
            int row  = nb0 + rloc;
            if (row < n) outf[(size_t)row * 64 + col] = acc[mt][reg] + sG[rloc * 68 + col] + bv;
        }
    }
}

extern "C" void kernel_launch(void* const* d_in, const int* in_sizes, int n_in,
                              void* d_out, int out_size, void* d_ws, size_t ws_size,
                              hipStream_t stream) {
    const float* x   = (const float*)d_in[0];
    const int*   ei  = (const int*)d_in[1];
    const float* Wl1 = (const float*)d_in[2];
    const float* bl1 = (const float*)d_in[3];
    const float* Wr1 = (const float*)d_in[4];
    const float* g1  = (const float*)d_in[5];
    const float* be1 = (const float*)d_in[6];
    const float* rm1 = (const float*)d_in[7];
    const float* rv1 = (const float*)d_in[8];
    const float* Wl2 = (const float*)d_in[9];
    const float* bl2 = (const float*)d_in[10];
    const float* Wr2 = (const float*)d_in[11];
    const float* g2  = (const float*)d_in[12];
    const float* be2 = (const float*)d_in[13];
    const float* rm2 = (const float*)d_in[14];
    const float* rv2 = (const float*)d_in[15];
    const float* Wl3 = (const float*)d_in[16];
    const float* bl3 = (const float*)d_in[17];
    const float* Wr3 = (const float*)d_in[18];

    const int N = in_sizes[0] / 128;
    const int E = in_sizes[1] / 2;
    const int* src = ei;
    const int* dst = ei + E;

    // workspace layout (feature buffers have N+1 rows; row N is the zero row)
    char* w = (char*)d_ws;
    auto au = [](size_t v) { return (v + 1023) & ~(size_t)1023; };
    size_t off = 0;
    int*            cnt    = (int*)(w + off);            off += au((size_t)N * 4);
    int*            b16    = (int*)(w + off);            off += au((size_t)N * 16 * 4);
    int*            bov    = (int*)(w + off);            off += au((size_t)N * (CAP - 16) * 4);
    unsigned short* xb     = (unsigned short*)(w + off); off += au((size_t)(N + 1) * 128 * 2);
    unsigned short* hb     = (unsigned short*)(w + off); off += au((size_t)(N + 1) * 128 * 2);
    unsigned short* hb2    = (unsigned short*)(w + off); off += au((size_t)(N + 1) * 128 * 2);
    unsigned short* t3b    = (unsigned short*)(w + off); off += au((size_t)(N + 1) * 64 * 2);
    unsigned short* Wp[6];
    Wp[0] = (unsigned short*)(w + off); off += au(128 * 128 * 2);  // Wl1
    Wp[1] = (unsigned short*)(w + off); off += au(128 * 128 * 2);  // Wr1
    Wp[2] = (unsigned short*)(w + off); off += au(128 * 128 * 2);  // Wl2
    Wp[3] = (unsigned short*)(w + off); off += au(128 * 128 * 2);  // Wr2
    Wp[4] = (unsigned short*)(w + off); off += au(128 * 64 * 2);   // Wl3
    Wp[5] = (unsigned short*)(w + off); off += au(128 * 64 * 2);   // Wr3
    float* P = (float*)(w + off); off += 2048;
    (void)ws_size; (void)n_in;

    (void)hipMemsetAsync(cnt, 0, (size_t)N * 4, stream);
    k_bucket<<<(E + 255) / 256, 256, 0, stream>>>(src, dst, E, cnt, b16, bov);
    dim3 pg(64, 7);
    k_prepack<<<pg, 256, 0, stream>>>(Wl1, Wr1, Wl2, Wr2, Wl3, Wr3,
                                      Wp[0], Wp[1], Wp[2], Wp[3], Wp[4], Wp[5],
                                      g1, be1, rm1, rv1, bl1, g2, be2, rm2, rv2, bl2, P,
                                      xb, hb, hb2, t3b, N);
    k_cvt<<<((N * 128 / 4) + 255) / 256, 256, 0, stream>>>(x, xb, N * 128 / 4);

    const int grid = (N + 31) / 32;

    // layer 1: hb = relu(bn(agg(x)@Wl1 + bl1 + x@Wr1))
    k_fused<false><<<grid, 256, 0, stream>>>(xb, cnt, b16, bov, Wp[0], Wp[1],
                                             P, P + 128, hb, nullptr, nullptr, N);
    // layer 2: hb2 = relu(bn(agg(hb)@Wl2 + bl2 + hb@Wr2)); t3b = hb2@Wl3
    k_fused<true><<<grid, 256, 0, stream>>>(hb, cnt, b16, bov, Wp[2], Wp[3],
                                            P + 256, P + 384, hb2, Wp[4], t3b, N);
    // layer 3: out = agg(t3b) + hb2@Wr3 + bl3
    k_final<<<grid, 256, 0, stream>>>(hb2, t3b, cnt, b16, bov, Wp[5], bl3, (float*)d_out, N);
}